// Round 3
// baseline (323071.729 us; speedup 1.0000x reference)
//
#include <hip/hip_runtime.h>
#include <hip/hip_bf16.h>

typedef unsigned short u16;
typedef unsigned int   u32;

#define S_  256
#define B_  512
#define H_  512
#define I_  70

// ---- bf16 helpers ----
__device__ __forceinline__ float bfu(u16 u) {
    return __uint_as_float(((u32)u) << 16);
}
__device__ __forceinline__ u16 f2bf_u(float f) {
    __hip_bfloat16 h = __float2bfloat16(f);
    u16 r;
    __builtin_memcpy(&r, &h, 2);
    return r;
}
__device__ __forceinline__ float sigmoidf_(float x) {
    x = fminf(fmaxf(x, -30.f), 30.f);
    return 1.f / (1.f + __expf(-x));
}
__device__ __forceinline__ float tanhf_(float x) {
    x = fminf(fmaxf(x, -15.f), 15.f);
    float e = __expf(2.f * x);
    return (e - 1.f) / (e + 1.f);
}

// ---- diagnostic sentinel: encodes ws_size in MiB so absmax reveals it ----
__global__ __launch_bounds__(256)
void k_sentinel(float* __restrict__ out, int n, float v) {
    int i = blockIdx.x * 256 + threadIdx.x;
    if (i < n) out[i] = v;
}

// ---- h0 = patient @ Wi2h.T + bi2h ; init both layers' h state ----
__global__ __launch_bounds__(256)
void k_h0(const float* __restrict__ X, const float* __restrict__ Wi2h,
          const float* __restrict__ bi2h, float* __restrict__ h1a,
          float* __restrict__ h2a) {
    int idx = blockIdx.x * 256 + threadIdx.x;   // B*H = 262144
    int b = idx >> 9, h = idx & 511;
    const float* xp = X + b * I_ + 64;          // patient = X[0,b,64:70]
    const float* wp = Wi2h + h * 6;
    float s = bi2h[h];
    #pragma unroll
    for (int j = 0; j < 6; j++) s += xp[j] * wp[j];
    h1a[idx] = s;
    h2a[idx] = s;
}

// ---- beff[e] = bcomb2[e] + sum_h Wcomb2[e][512+h]  (M==ones fold) ----
__global__ __launch_bounds__(256)
void k_beff(const float* __restrict__ Wcomb2, const float* __restrict__ bcomb2,
            float* __restrict__ beff) {
    int e = blockIdx.x * 256 + threadIdx.x;
    if (e >= 512) return;
    float s = bcomb2[e];
    const float* wp = Wcomb2 + (size_t)e * 1024 + 512;
    for (int k = 0; k < 512; k++) s += wp[k];
    beff[e] = s;
}

// ---- comb1 = concat(X[:,:,:64], M[:,:,:64]) @ Wcomb1.T + bcomb1 -> bf16 ----
__global__ __launch_bounds__(256)
void k_comb1(const float* __restrict__ X, const float* __restrict__ M,
             const float* __restrict__ Wcomb1, const float* __restrict__ bcomb1,
             u16* __restrict__ comb1) {
    __shared__ float W_s[128 * 68];   // [k][e], padded
    __shared__ float in_s[16 * 132];  // [r][k], padded
    const int tid = threadIdx.x;
    for (int i = tid; i < 64 * 128; i += 256) {
        int e = i >> 7, k = i & 127;
        W_s[k * 68 + e] = Wcomb1[i];
    }
    const size_t row0 = (size_t)blockIdx.x * 16;
    for (int i = tid; i < 16 * 128; i += 256) {
        int r = i >> 7, k = i & 127;
        size_t rg = row0 + r;
        in_s[r * 132 + k] = (k < 64) ? X[rg * I_ + k] : M[rg * I_ + (k - 64)];
    }
    __syncthreads();
    const int ty = tid >> 4, tx = tid & 15;
    float a0 = 0, a1 = 0, a2 = 0, a3 = 0;
    for (int k = 0; k < 128; k++) {
        float a = in_s[ty * 132 + k];
        float w[4];
        *(float4*)w = *(const float4*)&W_s[k * 68 + tx * 4];
        a0 = fmaf(a, w[0], a0); a1 = fmaf(a, w[1], a1);
        a2 = fmaf(a, w[2], a2); a3 = fmaf(a, w[3], a3);
    }
    size_t rg = row0 + ty;
    int e0 = tx * 4;
    ushort4 st;
    st.x = f2bf_u(a0 + bcomb1[e0 + 0]);
    st.y = f2bf_u(a1 + bcomb1[e0 + 1]);
    st.z = f2bf_u(a2 + bcomb1[e0 + 2]);
    st.w = f2bf_u(a3 + bcomb1[e0 + 3]);
    *(ushort4*)&comb1[rg * 64 + e0] = st;
}

// ---- one masked-GRU step; writes hnxt (f32) only ----
// grid (32,16): blockIdx.x -> h-tile of 16, blockIdx.y -> b-tile of 32.
template<int D>
__global__ __launch_bounds__(256)
void k_gru_step(const u16* __restrict__ comb,   // [.][B][D] bf16 (t pre-applied or t idx)
                const float* __restrict__ Wih,  // [1536*D]
                const float* __restrict__ Whh,  // [1536*512]
                const float* __restrict__ bih, const float* __restrict__ bhh,
                const float* __restrict__ mask, // [.][B]
                const float* __restrict__ hcur, float* __restrict__ hnxt,
                const int t) {
    const int tid = threadIdx.x;
    const int tx = tid & 15;
    const int ty = tid >> 4;
    const int h  = blockIdx.x * 16 + tx;
    const int b  = blockIdx.y * 32 + ty * 2;

    const float* wh0 = Whh + (size_t)h * 512;
    const float* wh1 = Whh + (size_t)(512 + h) * 512;
    const float* wh2 = Whh + (size_t)(1024 + h) * 512;
    const float* wi0 = Wih + (size_t)h * D;
    const float* wi1 = Wih + (size_t)(512 + h) * D;
    const float* wi2 = Wih + (size_t)(1024 + h) * D;

    const float* hrow0 = hcur + (size_t)b * 512;
    const float* hrow1 = hcur + (size_t)(b + 1) * 512;
    const u16* crow0 = comb + ((size_t)t * 512 + b) * D;
    const u16* crow1 = comb + ((size_t)t * 512 + b + 1) * D;

    float ar0 = bhh[h], az0 = bhh[512 + h], an0 = bhh[1024 + h];
    float ar1 = ar0, az1 = az0, an1 = an0;
    float br0 = bih[h], bz0 = bih[512 + h], bn0 = bih[1024 + h];
    float br1 = br0, bz1 = bz0, bn1 = bn0;

    for (int k = 0; k < 512; k += 4) {
        float w0[4], w1[4], w2[4], h0v[4], h1v[4];
        *(float4*)w0  = *(const float4*)(wh0 + k);
        *(float4*)w1  = *(const float4*)(wh1 + k);
        *(float4*)w2  = *(const float4*)(wh2 + k);
        *(float4*)h0v = *(const float4*)(hrow0 + k);
        *(float4*)h1v = *(const float4*)(hrow1 + k);
        #pragma unroll
        for (int kk = 0; kk < 4; kk++) {
            ar0 = fmaf(h0v[kk], w0[kk], ar0);
            az0 = fmaf(h0v[kk], w1[kk], az0);
            an0 = fmaf(h0v[kk], w2[kk], an0);
            ar1 = fmaf(h1v[kk], w0[kk], ar1);
            az1 = fmaf(h1v[kk], w1[kk], az1);
            an1 = fmaf(h1v[kk], w2[kk], an1);
        }
    }
    for (int k = 0; k < D; k += 4) {
        float w0[4], w1[4], w2[4];
        *(float4*)w0 = *(const float4*)(wi0 + k);
        *(float4*)w1 = *(const float4*)(wi1 + k);
        *(float4*)w2 = *(const float4*)(wi2 + k);
        ushort4 c0u = *(const ushort4*)(crow0 + k);
        ushort4 c1u = *(const ushort4*)(crow1 + k);
        float c0v[4] = {bfu(c0u.x), bfu(c0u.y), bfu(c0u.z), bfu(c0u.w)};
        float c1v[4] = {bfu(c1u.x), bfu(c1u.y), bfu(c1u.z), bfu(c1u.w)};
        #pragma unroll
        for (int kk = 0; kk < 4; kk++) {
            br0 = fmaf(c0v[kk], w0[kk], br0);
            bz0 = fmaf(c0v[kk], w1[kk], bz0);
            bn0 = fmaf(c0v[kk], w2[kk], bn0);
            br1 = fmaf(c1v[kk], w0[kk], br1);
            bz1 = fmaf(c1v[kk], w1[kk], bz1);
            bn1 = fmaf(c1v[kk], w2[kk], bn1);
        }
    }
    {
        float hold = hrow0[h];
        float r = sigmoidf_(br0 + ar0);
        float z = sigmoidf_(bz0 + az0);
        float n = tanhf_(bn0 + r * an0);
        float m = mask[t * 512 + b];
        hnxt[(size_t)b * 512 + h] = ((1.f - z) * n + z * hold) * m + hold * (1.f - m);
    }
    {
        float hold = hrow1[h];
        float r = sigmoidf_(br1 + ar1);
        float z = sigmoidf_(bz1 + az1);
        float n = tanhf_(bn1 + r * an1);
        float m = mask[t * 512 + b + 1];
        hnxt[(size_t)(b + 1) * 512 + h] = ((1.f - z) * n + z * hold) * m + hold * (1.f - m);
    }
}

// ---- B1: y = LN(cat(comb1_t, h1_t) @ Wc21.T + bc21; g1,b1);
//          comb2_t = y @ Wcomb2[:, :512].T + beff   -> bf16 slice [B][512]
// block: 256 thr = 8 rows x 32 lanes; lane covers 16 outs. 64 blocks.
__global__ __launch_bounds__(256)
void k_out1comb2(const u16* __restrict__ c1t,   // comb1 + t*B*64
                 const float* __restrict__ h1,  // [B][512] f32
                 const float* __restrict__ Wc21,// [512][576]
                 const float* __restrict__ bc21,
                 const float* __restrict__ g1, const float* __restrict__ b1,
                 const float* __restrict__ Wcomb2, // [512][1024]
                 const float* __restrict__ beff,
                 u16* __restrict__ c2t) {       // [B][512] bf16
    __shared__ float x_s[8 * 576];
    __shared__ float y_s[8 * 512];
    const int tid = threadIdx.x;
    const int ty = tid >> 5, lane = tid & 31;
    const int row = blockIdx.x * 8 + ty;
    // stage x = cat(comb1_t[row], h1[row])
    for (int k = lane; k < 64; k += 32) x_s[ty * 576 + k] = bfu(c1t[row * 64 + k]);
    for (int k = lane; k < 512; k += 32) x_s[ty * 576 + 64 + k] = h1[(size_t)row * 512 + k];
    __syncthreads();
    const int o0 = lane * 16;
    float acc[16];
    #pragma unroll
    for (int j = 0; j < 16; j++) acc[j] = 0.f;
    const float* xr = x_s + ty * 576;
    for (int k = 0; k < 576; k += 4) {
        float xv[4];
        *(float4*)xv = *(const float4*)(xr + k);
        #pragma unroll
        for (int j = 0; j < 16; j++) {
            float wv[4];
            *(float4*)wv = *(const float4*)(Wc21 + (size_t)(o0 + j) * 576 + k);
            acc[j] = fmaf(xv[0], wv[0], acc[j]);
            acc[j] = fmaf(xv[1], wv[1], acc[j]);
            acc[j] = fmaf(xv[2], wv[2], acc[j]);
            acc[j] = fmaf(xv[3], wv[3], acc[j]);
        }
    }
    float sum = 0.f, ssq = 0.f;
    #pragma unroll
    for (int j = 0; j < 16; j++) {
        acc[j] += bc21[o0 + j];
        sum += acc[j]; ssq += acc[j] * acc[j];
    }
    #pragma unroll
    for (int m = 1; m < 32; m <<= 1) {       // reduce within 32-lane row group
        sum += __shfl_xor(sum, m, 64);
        ssq += __shfl_xor(ssq, m, 64);
    }
    const float mu   = sum * (1.f / 512.f);
    const float rstd = rsqrtf(ssq * (1.f / 512.f) - mu * mu + 1e-5f);
    #pragma unroll
    for (int j = 0; j < 16; j++)
        y_s[ty * 512 + o0 + j] = (acc[j] - mu) * rstd * g1[o0 + j] + b1[o0 + j];
    __syncthreads();
    // comb2 slice
    float c2[16];
    #pragma unroll
    for (int j = 0; j < 16; j++) c2[j] = beff[o0 + j];
    const float* yr = y_s + ty * 512;
    for (int k = 0; k < 512; k += 4) {
        float yv[4];
        *(float4*)yv = *(const float4*)(yr + k);
        #pragma unroll
        for (int j = 0; j < 16; j++) {
            float wv[4];
            *(float4*)wv = *(const float4*)(Wcomb2 + (size_t)(o0 + j) * 1024 + k);
            c2[j] = fmaf(yv[0], wv[0], c2[j]);
            c2[j] = fmaf(yv[1], wv[1], c2[j]);
            c2[j] = fmaf(yv[2], wv[2], c2[j]);
            c2[j] = fmaf(yv[3], wv[3], c2[j]);
        }
    }
    #pragma unroll
    for (int j4 = 0; j4 < 4; j4++) {
        ushort4 st;
        st.x = f2bf_u(c2[j4 * 4 + 0]);
        st.y = f2bf_u(c2[j4 * 4 + 1]);
        st.z = f2bf_u(c2[j4 * 4 + 2]);
        st.w = f2bf_u(c2[j4 * 4 + 3]);
        *(ushort4*)&c2t[(size_t)row * 512 + o0 + j4 * 4] = st;
    }
}

// ---- B2: y = LN(cat(comb2_t, h2_t) @ Wc22.T + bc22; g2,b2);
//          head: relu(y@Wnn1.T+bnn1) -> LN8(g3,b3) -> @Wnn2.T+bnn2 -> out[t]
__global__ __launch_bounds__(256)
void k_out2head(const u16* __restrict__ c2t,   // [B][512] bf16
                const float* __restrict__ h2,  // [B][512] f32
                const float* __restrict__ Wc22,// [512][1024]
                const float* __restrict__ bc22,
                const float* __restrict__ g2, const float* __restrict__ b2,
                const float* __restrict__ Wnn1, const float* __restrict__ bnn1,
                const float* __restrict__ g3, const float* __restrict__ b3,
                const float* __restrict__ Wnn2, const float* __restrict__ bnn2,
                float* __restrict__ outt) {    // out + t*B*2
    __shared__ float x_s[8 * 1024];
    __shared__ float y_s[8 * 512];
    const int tid = threadIdx.x;
    const int ty = tid >> 5, lane = tid & 31;
    const int row = blockIdx.x * 8 + ty;
    for (int k = lane; k < 512; k += 32) {
        x_s[ty * 1024 + k] = bfu(c2t[(size_t)row * 512 + k]);
        x_s[ty * 1024 + 512 + k] = h2[(size_t)row * 512 + k];
    }
    __syncthreads();
    const int o0 = lane * 16;
    float acc[16];
    #pragma unroll
    for (int j = 0; j < 16; j++) acc[j] = 0.f;
    const float* xr = x_s + ty * 1024;
    for (int k = 0; k < 1024; k += 4) {
        float xv[4];
        *(float4*)xv = *(const float4*)(xr + k);
        #pragma unroll
        for (int j = 0; j < 16; j++) {
            float wv[4];
            *(float4*)wv = *(const float4*)(Wc22 + (size_t)(o0 + j) * 1024 + k);
            acc[j] = fmaf(xv[0], wv[0], acc[j]);
            acc[j] = fmaf(xv[1], wv[1], acc[j]);
            acc[j] = fmaf(xv[2], wv[2], acc[j]);
            acc[j] = fmaf(xv[3], wv[3], acc[j]);
        }
    }
    float sum = 0.f, ssq = 0.f;
    #pragma unroll
    for (int j = 0; j < 16; j++) {
        acc[j] += bc22[o0 + j];
        sum += acc[j]; ssq += acc[j] * acc[j];
    }
    #pragma unroll
    for (int m = 1; m < 32; m <<= 1) {
        sum += __shfl_xor(sum, m, 64);
        ssq += __shfl_xor(ssq, m, 64);
    }
    const float mu   = sum * (1.f / 512.f);
    const float rstd = rsqrtf(ssq * (1.f / 512.f) - mu * mu + 1e-5f);
    float yv16[16];
    #pragma unroll
    for (int j = 0; j < 16; j++)
        yv16[j] = (acc[j] - mu) * rstd * g2[o0 + j] + b2[o0 + j];
    // head partials: p[o] over this thread's 16 k's
    float p[8];
    #pragma unroll
    for (int o = 0; o < 8; o++) {
        const float* wp = Wnn1 + o * 512 + o0;
        float s = 0.f;
        #pragma unroll
        for (int j = 0; j < 16; j++) s = fmaf(yv16[j], wp[j], s);
        p[o] = s;
    }
    #pragma unroll
    for (int m = 1; m < 32; m <<= 1) {
        #pragma unroll
        for (int o = 0; o < 8; o++) p[o] += __shfl_xor(p[o], m, 64);
    }
    if (lane == 0) {
        float tv[8], m8 = 0.f;
        #pragma unroll
        for (int o = 0; o < 8; o++) { tv[o] = fmaxf(p[o] + bnn1[o], 0.f); m8 += tv[o]; }
        m8 *= 0.125f;
        float var = 0.f;
        #pragma unroll
        for (int o = 0; o < 8; o++) { float d = tv[o] - m8; var += d * d; }
        var *= 0.125f;
        const float rstd8 = rsqrtf(var + 1e-5f);
        float o0v = bnn2[0], o1v = bnn2[1];
        #pragma unroll
        for (int o = 0; o < 8; o++) {
            float v = (tv[o] - m8) * rstd8 * g3[o] + b3[o];
            o0v += v * Wnn2[o];
            o1v += v * Wnn2[8 + o];
        }
        outt[row * 2 + 0] = o0v;
        outt[row * 2 + 1] = o1v;
    }
}

extern "C" void kernel_launch(void* const* d_in, const int* in_sizes, int n_in,
                              void* d_out, int out_size, void* d_ws, size_t ws_size,
                              hipStream_t stream) {
    const float* X      = (const float*)d_in[0];
    const float* M      = (const float*)d_in[1];
    const float* mask   = (const float*)d_in[2];
    const float* Wi2h   = (const float*)d_in[3];
    const float* bi2h   = (const float*)d_in[4];
    const float* Wcomb1 = (const float*)d_in[5];
    const float* bcomb1 = (const float*)d_in[6];
    const float* Wih1   = (const float*)d_in[7];
    const float* Whh1   = (const float*)d_in[8];
    const float* bih1   = (const float*)d_in[9];
    const float* bhh1   = (const float*)d_in[10];
    const float* Wc21   = (const float*)d_in[11];
    const float* bc21   = (const float*)d_in[12];
    const float* Wcomb2 = (const float*)d_in[13];
    const float* bcomb2 = (const float*)d_in[14];
    const float* Wih2   = (const float*)d_in[15];
    const float* Whh2   = (const float*)d_in[16];
    const float* bih2   = (const float*)d_in[17];
    const float* bhh2   = (const float*)d_in[18];
    const float* Wc22   = (const float*)d_in[19];
    const float* bc22   = (const float*)d_in[20];
    const float* g1     = (const float*)d_in[21];
    const float* b1     = (const float*)d_in[22];
    const float* g2     = (const float*)d_in[23];
    const float* b2     = (const float*)d_in[24];
    const float* g3     = (const float*)d_in[25];
    const float* b3     = (const float*)d_in[26];
    const float* Wnn1   = (const float*)d_in[27];
    const float* bnn1   = (const float*)d_in[28];
    const float* Wnn2   = (const float*)d_in[29];
    const float* bnn2   = (const float*)d_in[30];
    float* out = (float*)d_out;

    // workspace layout (~21.3 MiB)
    const size_t SZ_COMB1 = (size_t)S_ * B_ * 64 * 2;   // 16.78 MB
    const size_t SZ_HX    = (size_t)B_ * H_ * 4;        // 1 MB each
    const size_t SZ_C2T   = (size_t)B_ * 512 * 2;       // 0.52 MB
    const size_t NEED = SZ_COMB1 + 4 * SZ_HX + SZ_C2T + 4096;
    if (ws_size < NEED) {
        // encode ws_size (MiB) into output: absmax ~= 1e4 + MiB
        float v = 1.0e4f + (float)(ws_size >> 20);
        k_sentinel<<<(out_size + 255) / 256, 256, 0, stream>>>(out, out_size, v);
        return;
    }
    char* ws = (char*)d_ws;
    u16* comb1 = (u16*)ws;   ws += SZ_COMB1;
    float* h1a = (float*)ws; ws += SZ_HX;
    float* h1b = (float*)ws; ws += SZ_HX;
    float* h2a = (float*)ws; ws += SZ_HX;
    float* h2b = (float*)ws; ws += SZ_HX;
    u16* c2t   = (u16*)ws;   ws += SZ_C2T;

    k_h0<<<1024, 256, 0, stream>>>(X, Wi2h, bi2h, h1a, h2a);
    k_beff<<<2, 256, 0, stream>>>(Wcomb2, bcomb2, (float*)(d_out));  // temp? NO
    // beff must persist across the whole loop; put it in ws tail instead:
    // (we still have room: reuse bytes right after c2t)
    float* beff = (float*)ws;
    k_beff<<<2, 256, 0, stream>>>(Wcomb2, bcomb2, beff);
    k_comb1<<<8192, 256, 0, stream>>>(X, M, Wcomb1, bcomb1, comb1);

    for (int t = 0; t < S_; t++) {
        const float* h1c = (t & 1) ? h1b : h1a;
        float*       h1n = (t & 1) ? h1a : h1b;
        const float* h2c = (t & 1) ? h2b : h2a;
        float*       h2n = (t & 1) ? h2a : h2b;
        // A1: GRU layer-1 step
        k_gru_step<64><<<dim3(32, 16), 256, 0, stream>>>(
            comb1, Wih1, Whh1, bih1, bhh1, mask, h1c, h1n, t);
        // B1: out1 + LN1 + comb2 slice
        k_out1comb2<<<64, 256, 0, stream>>>(
            comb1 + (size_t)t * B_ * 64, h1n, Wc21, bc21, g1, b1,
            Wcomb2, beff, c2t);
        // A2: GRU layer-2 step (comb slice, t=0; mask pre-offset)
        k_gru_step<512><<<dim3(32, 16), 256, 0, stream>>>(
            c2t, Wih2, Whh2, bih2, bhh2, mask + (size_t)t * B_, h2c, h2n, 0);
        // B2: out2 + LN2 + head -> out[t]
        k_out2head<<<64, 256, 0, stream>>>(
            c2t, h2n, Wc22, bc22, g2, b2, Wnn1, bnn1, g3, b3, Wnn2, bnn2,
            out + (size_t)t * B_ * 2);
    }
}

// Round 4
// 88375.934 us; speedup vs baseline: 3.6557x; 3.6557x over previous
//
#include <hip/hip_runtime.h>
#include <hip/hip_bf16.h>

typedef unsigned short u16;
typedef unsigned int   u32;

#define S_  256
#define B_  512
#define H_  512
#define I_  70

// ---- bf16 helpers ----
__device__ __forceinline__ float bfu(u16 u) {
    return __uint_as_float(((u32)u) << 16);
}
__device__ __forceinline__ u16 f2bf_u(float f) {
    __hip_bfloat16 h = __float2bfloat16(f);
    u16 r;
    __builtin_memcpy(&r, &h, 2);
    return r;
}
__device__ __forceinline__ float sigmoidf_(float x) {
    x = fminf(fmaxf(x, -30.f), 30.f);
    return 1.f / (1.f + __expf(-x));
}
__device__ __forceinline__ float tanhf_(float x) {
    x = fminf(fmaxf(x, -15.f), 15.f);
    float e = __expf(2.f * x);
    return (e - 1.f) / (e + 1.f);
}

// ---- diagnostic sentinel: encodes ws_size in MiB so absmax reveals it ----
__global__ __launch_bounds__(256)
void k_sentinel(float* __restrict__ out, int n, float v) {
    int i = blockIdx.x * 256 + threadIdx.x;
    if (i < n) out[i] = v;
}

// ---- h0 = patient @ Wi2h.T + bi2h ; init both layers' h state ----
__global__ __launch_bounds__(256)
void k_h0(const float* __restrict__ X, const float* __restrict__ Wi2h,
          const float* __restrict__ bi2h, float* __restrict__ h1a,
          float* __restrict__ h2a) {
    int idx = blockIdx.x * 256 + threadIdx.x;   // B*H = 262144
    int b = idx >> 9, h = idx & 511;
    const float* xp = X + b * I_ + 64;
    const float* wp = Wi2h + h * 6;
    float s = bi2h[h];
    #pragma unroll
    for (int j = 0; j < 6; j++) s += xp[j] * wp[j];
    h1a[idx] = s;
    h2a[idx] = s;
}

// ---- beff[e] = bcomb2[e] + sum_h Wcomb2[e][512+h]  (M==ones fold) ----
__global__ __launch_bounds__(256)
void k_beff(const float* __restrict__ Wcomb2, const float* __restrict__ bcomb2,
            float* __restrict__ beff) {
    int e = blockIdx.x * 256 + threadIdx.x;
    if (e >= 512) return;
    float s = bcomb2[e];
    const float* wp = Wcomb2 + (size_t)e * 1024 + 512;
    for (int k = 0; k < 512; k++) s += wp[k];
    beff[e] = s;
}

// ---- comb1 = concat(X[:,:,:64], M[:,:,:64]) @ Wcomb1.T + bcomb1 -> bf16 ----
__global__ __launch_bounds__(256)
void k_comb1(const float* __restrict__ X, const float* __restrict__ M,
             const float* __restrict__ Wcomb1, const float* __restrict__ bcomb1,
             u16* __restrict__ comb1) {
    __shared__ float W_s[128 * 68];   // [k][e], padded
    __shared__ float in_s[16 * 132];  // [r][k], padded
    const int tid = threadIdx.x;
    for (int i = tid; i < 64 * 128; i += 256) {
        int e = i >> 7, k = i & 127;
        W_s[k * 68 + e] = Wcomb1[i];
    }
    const size_t row0 = (size_t)blockIdx.x * 16;
    for (int i = tid; i < 16 * 128; i += 256) {
        int r = i >> 7, k = i & 127;
        size_t rg = row0 + r;
        in_s[r * 132 + k] = (k < 64) ? X[rg * I_ + k] : M[rg * I_ + (k - 64)];
    }
    __syncthreads();
    const int ty = tid >> 4, tx = tid & 15;
    float a0 = 0, a1 = 0, a2 = 0, a3 = 0;
    for (int k = 0; k < 128; k++) {
        float a = in_s[ty * 132 + k];
        float w[4];
        *(float4*)w = *(const float4*)&W_s[k * 68 + tx * 4];
        a0 = fmaf(a, w[0], a0); a1 = fmaf(a, w[1], a1);
        a2 = fmaf(a, w[2], a2); a3 = fmaf(a, w[3], a3);
    }
    size_t rg = row0 + ty;
    int e0 = tx * 4;
    ushort4 st;
    st.x = f2bf_u(a0 + bcomb1[e0 + 0]);
    st.y = f2bf_u(a1 + bcomb1[e0 + 1]);
    st.z = f2bf_u(a2 + bcomb1[e0 + 2]);
    st.w = f2bf_u(a3 + bcomb1[e0 + 3]);
    *(ushort4*)&comb1[rg * 64 + e0] = st;
}

// ---- one masked-GRU step, LDS-staged weights (coalesced) ----
// grid (64,8): blockIdx.x -> h-tile of 8, blockIdx.y -> b-tile of 64.
// thread: hl=tid&7 -> local h; ty=tid>>3 -> pair of batch rows.
// Phase 1: stage Whh rows (24x512 f32, stride 516) -> gh accums.
// Phase 2: restage with Wih rows (24xD) -> gi accums. Gates fused.
template<int D>
__global__ __launch_bounds__(256)
void k_gru_step(const u16* __restrict__ comb,   // [.][B][D] bf16
                const float* __restrict__ Wih,  // [1536*D]
                const float* __restrict__ Whh,  // [1536*512]
                const float* __restrict__ bih, const float* __restrict__ bhh,
                const float* __restrict__ mask, // [.][B]
                const float* __restrict__ hcur, float* __restrict__ hnxt,
                const int t) {
    __shared__ float W_s[24 * 516];             // 49.5 KB
    const int tid = threadIdx.x;
    const int hl = tid & 7;
    const int ty = tid >> 3;                    // 0..31
    const int h0 = blockIdx.x * 8;
    const int h  = h0 + hl;
    const int b  = blockIdx.y * 64 + ty * 2;

    // phase 1: stage Whh (24 rows x 512 f32), coalesced
    for (int i = tid; i < 24 * 128; i += 256) {
        int r = i >> 7, kq = i & 127;
        int g = r >> 3, hh = r & 7;
        *(float4*)&W_s[r * 516 + kq * 4] =
            *(const float4*)&Whh[((size_t)(g * 512 + h0 + hh)) * 512 + kq * 4];
    }
    __syncthreads();

    const float* hr0 = hcur + (size_t)b * 512;
    const float* hr1 = hcur + (size_t)(b + 1) * 512;
    float gh00 = bhh[h], gh10 = bhh[512 + h], gh20 = bhh[1024 + h];
    float gh01 = gh00, gh11 = gh10, gh21 = gh20;
    {
        const float* w0p = &W_s[(0 * 8 + hl) * 516];
        const float* w1p = &W_s[(1 * 8 + hl) * 516];
        const float* w2p = &W_s[(2 * 8 + hl) * 516];
        for (int k = 0; k < 512; k += 4) {
            float4 w0 = *(const float4*)(w0p + k);
            float4 w1 = *(const float4*)(w1p + k);
            float4 w2 = *(const float4*)(w2p + k);
            float4 ha = *(const float4*)(hr0 + k);
            float4 hb = *(const float4*)(hr1 + k);
            gh00 = fmaf(w0.x, ha.x, gh00); gh00 = fmaf(w0.y, ha.y, gh00);
            gh00 = fmaf(w0.z, ha.z, gh00); gh00 = fmaf(w0.w, ha.w, gh00);
            gh10 = fmaf(w1.x, ha.x, gh10); gh10 = fmaf(w1.y, ha.y, gh10);
            gh10 = fmaf(w1.z, ha.z, gh10); gh10 = fmaf(w1.w, ha.w, gh10);
            gh20 = fmaf(w2.x, ha.x, gh20); gh20 = fmaf(w2.y, ha.y, gh20);
            gh20 = fmaf(w2.z, ha.z, gh20); gh20 = fmaf(w2.w, ha.w, gh20);
            gh01 = fmaf(w0.x, hb.x, gh01); gh01 = fmaf(w0.y, hb.y, gh01);
            gh01 = fmaf(w0.z, hb.z, gh01); gh01 = fmaf(w0.w, hb.w, gh01);
            gh11 = fmaf(w1.x, hb.x, gh11); gh11 = fmaf(w1.y, hb.y, gh11);
            gh11 = fmaf(w1.z, hb.z, gh11); gh11 = fmaf(w1.w, hb.w, gh11);
            gh21 = fmaf(w2.x, hb.x, gh21); gh21 = fmaf(w2.y, hb.y, gh21);
            gh21 = fmaf(w2.z, hb.z, gh21); gh21 = fmaf(w2.w, hb.w, gh21);
        }
    }
    __syncthreads();
    // phase 2: stage Wih (24 rows x D f32)
    constexpr int KQ = D / 4;
    constexpr int WST = (D == 512) ? 516 : (D + 4);
    for (int i = tid; i < 24 * KQ; i += 256) {
        int r = i / KQ, kq = i % KQ;
        int g = r >> 3, hh = r & 7;
        *(float4*)&W_s[r * WST + kq * 4] =
            *(const float4*)&Wih[((size_t)(g * 512 + h0 + hh)) * D + kq * 4];
    }
    __syncthreads();

    const u16* cr0 = comb + ((size_t)t * 512 + b) * D;
    const u16* cr1 = comb + ((size_t)t * 512 + b + 1) * D;
    float gi00 = bih[h], gi10 = bih[512 + h], gi20 = bih[1024 + h];
    float gi01 = gi00, gi11 = gi10, gi21 = gi20;
    {
        const float* w0p = &W_s[(0 * 8 + hl) * WST];
        const float* w1p = &W_s[(1 * 8 + hl) * WST];
        const float* w2p = &W_s[(2 * 8 + hl) * WST];
        for (int k = 0; k < D; k += 4) {
            float4 w0 = *(const float4*)(w0p + k);
            float4 w1 = *(const float4*)(w1p + k);
            float4 w2 = *(const float4*)(w2p + k);
            ushort4 cu0 = *(const ushort4*)(cr0 + k);
            ushort4 cu1 = *(const ushort4*)(cr1 + k);
            float ca[4] = {bfu(cu0.x), bfu(cu0.y), bfu(cu0.z), bfu(cu0.w)};
            float cb[4] = {bfu(cu1.x), bfu(cu1.y), bfu(cu1.z), bfu(cu1.w)};
            gi00 = fmaf(w0.x, ca[0], gi00); gi00 = fmaf(w0.y, ca[1], gi00);
            gi00 = fmaf(w0.z, ca[2], gi00); gi00 = fmaf(w0.w, ca[3], gi00);
            gi10 = fmaf(w1.x, ca[0], gi10); gi10 = fmaf(w1.y, ca[1], gi10);
            gi10 = fmaf(w1.z, ca[2], gi10); gi10 = fmaf(w1.w, ca[3], gi10);
            gi20 = fmaf(w2.x, ca[0], gi20); gi20 = fmaf(w2.y, ca[1], gi20);
            gi20 = fmaf(w2.z, ca[2], gi20); gi20 = fmaf(w2.w, ca[3], gi20);
            gi01 = fmaf(w0.x, cb[0], gi01); gi01 = fmaf(w0.y, cb[1], gi01);
            gi01 = fmaf(w0.z, cb[2], gi01); gi01 = fmaf(w0.w, cb[3], gi01);
            gi11 = fmaf(w1.x, cb[0], gi11); gi11 = fmaf(w1.y, cb[1], gi11);
            gi11 = fmaf(w1.z, cb[2], gi11); gi11 = fmaf(w1.w, cb[3], gi11);
            gi21 = fmaf(w2.x, cb[0], gi21); gi21 = fmaf(w2.y, cb[1], gi21);
            gi21 = fmaf(w2.z, cb[2], gi21); gi21 = fmaf(w2.w, cb[3], gi21);
        }
    }
    // gates + mask merge
    {
        float hold = hr0[h];
        float r = sigmoidf_(gi00 + gh00);
        float z = sigmoidf_(gi10 + gh10);
        float n = tanhf_(gi20 + r * gh20);
        float m = mask[t * 512 + b];
        hnxt[(size_t)b * 512 + h] = ((1.f - z) * n + z * hold) * m + hold * (1.f - m);
    }
    {
        float hold = hr1[h];
        float r = sigmoidf_(gi01 + gh01);
        float z = sigmoidf_(gi11 + gh11);
        float n = tanhf_(gi21 + r * gh21);
        float m = mask[t * 512 + b + 1];
        hnxt[(size_t)(b + 1) * 512 + h] = ((1.f - z) * n + z * hold) * m + hold * (1.f - m);
    }
}

// ---- B1: y = LN(cat(comb1_t, h1_t) @ Wc21.T + bc21; g1,b1);
//          comb2_t = y @ Wcomb2[:, :512].T + beff -> bf16 [B][512]
// 128 blocks x 4 rows. k-cooperative: 16 k-lanes x 4 o per wave, coalesced W.
__global__ __launch_bounds__(256)
void k_out1comb2(const u16* __restrict__ c1t, const float* __restrict__ h1,
                 const float* __restrict__ Wc21, const float* __restrict__ bc21,
                 const float* __restrict__ g1, const float* __restrict__ b1,
                 const float* __restrict__ Wcomb2, const float* __restrict__ beff,
                 u16* __restrict__ c2t) {
    __shared__ float x_s[4 * 576];
    __shared__ float y_s[4 * 512];
    const int tid = threadIdx.x;
    const int row0 = blockIdx.x * 4;
    for (int i = tid; i < 4 * 64; i += 256) {
        int r = i >> 6, k = i & 63;
        x_s[r * 576 + k] = bfu(c1t[(size_t)(row0 + r) * 64 + k]);
    }
    for (int i = tid; i < 4 * 512; i += 256) {
        int r = i >> 9, k = i & 511;
        x_s[r * 576 + 64 + k] = h1[(size_t)(row0 + r) * 512 + k];
    }
    __syncthreads();
    const int w = tid >> 6, lane = tid & 63;
    const int cg = lane >> 4, kl = lane & 15;
    // GEMM1: out1 + bias
    for (int i = 0; i < 32; i++) {
        int o = i * 16 + w * 4 + cg;
        const float* wrow = Wc21 + (size_t)o * 576;
        float racc[4] = {0.f, 0.f, 0.f, 0.f};
        #pragma unroll
        for (int g = 0; g < 9; g++) {
            int k = g * 64 + kl * 4;
            float4 wv = *(const float4*)(wrow + k);
            #pragma unroll
            for (int r = 0; r < 4; r++) {
                float4 xv = *(const float4*)(x_s + r * 576 + k);
                racc[r] = fmaf(wv.x, xv.x, racc[r]);
                racc[r] = fmaf(wv.y, xv.y, racc[r]);
                racc[r] = fmaf(wv.z, xv.z, racc[r]);
                racc[r] = fmaf(wv.w, xv.w, racc[r]);
            }
        }
        #pragma unroll
        for (int r = 0; r < 4; r++) {
            racc[r] += __shfl_xor(racc[r], 1, 64);
            racc[r] += __shfl_xor(racc[r], 2, 64);
            racc[r] += __shfl_xor(racc[r], 4, 64);
            racc[r] += __shfl_xor(racc[r], 8, 64);
        }
        if (kl == 0) {
            float bb = bc21[o];
            #pragma unroll
            for (int r = 0; r < 4; r++) y_s[r * 512 + o] = racc[r] + bb;
        }
    }
    __syncthreads();
    // LN row w
    {
        float v[8], sum = 0.f, ssq = 0.f;
        #pragma unroll
        for (int j = 0; j < 8; j++) {
            v[j] = y_s[w * 512 + lane * 8 + j];
            sum += v[j]; ssq += v[j] * v[j];
        }
        #pragma unroll
        for (int m = 1; m < 64; m <<= 1) {
            sum += __shfl_xor(sum, m, 64);
            ssq += __shfl_xor(ssq, m, 64);
        }
        float mu = sum * (1.f / 512.f);
        float rstd = rsqrtf(ssq * (1.f / 512.f) - mu * mu + 1e-5f);
        #pragma unroll
        for (int j = 0; j < 8; j++) {
            int o = lane * 8 + j;
            y_s[w * 512 + o] = (v[j] - mu) * rstd * g1[o] + b1[o];
        }
    }
    __syncthreads();
    // GEMM2: comb2 slice
    for (int i = 0; i < 32; i++) {
        int o = i * 16 + w * 4 + cg;
        const float* wrow = Wcomb2 + (size_t)o * 1024;
        float racc[4] = {0.f, 0.f, 0.f, 0.f};
        #pragma unroll
        for (int g = 0; g < 8; g++) {
            int k = g * 64 + kl * 4;
            float4 wv = *(const float4*)(wrow + k);
            #pragma unroll
            for (int r = 0; r < 4; r++) {
                float4 xv = *(const float4*)(y_s + r * 512 + k);
                racc[r] = fmaf(wv.x, xv.x, racc[r]);
                racc[r] = fmaf(wv.y, xv.y, racc[r]);
                racc[r] = fmaf(wv.z, xv.z, racc[r]);
                racc[r] = fmaf(wv.w, xv.w, racc[r]);
            }
        }
        #pragma unroll
        for (int r = 0; r < 4; r++) {
            racc[r] += __shfl_xor(racc[r], 1, 64);
            racc[r] += __shfl_xor(racc[r], 2, 64);
            racc[r] += __shfl_xor(racc[r], 4, 64);
            racc[r] += __shfl_xor(racc[r], 8, 64);
        }
        if (kl == 0) {
            float bb = beff[o];
            #pragma unroll
            for (int r = 0; r < 4; r++)
                c2t[(size_t)(row0 + r) * 512 + o] = f2bf_u(racc[r] + bb);
        }
    }
}

// ---- B2: y = LN(cat(comb2_t, h2_t) @ Wc22.T + bc22; g2,b2); fused head ----
__global__ __launch_bounds__(256)
void k_out2head(const u16* __restrict__ c2t, const float* __restrict__ h2,
                const float* __restrict__ Wc22, const float* __restrict__ bc22,
                const float* __restrict__ g2, const float* __restrict__ b2,
                const float* __restrict__ Wnn1, const float* __restrict__ bnn1,
                const float* __restrict__ g3, const float* __restrict__ b3,
                const float* __restrict__ Wnn2, const float* __restrict__ bnn2,
                float* __restrict__ outt) {
    __shared__ float x_s[4 * 1024];
    __shared__ float y_s[4 * 512];
    const int tid = threadIdx.x;
    const int row0 = blockIdx.x * 4;
    for (int i = tid; i < 4 * 512; i += 256) {
        int r = i >> 9, k = i & 511;
        x_s[r * 1024 + k] = bfu(c2t[(size_t)(row0 + r) * 512 + k]);
        x_s[r * 1024 + 512 + k] = h2[(size_t)(row0 + r) * 512 + k];
    }
    __syncthreads();
    const int w = tid >> 6, lane = tid & 63;
    const int cg = lane >> 4, kl = lane & 15;
    for (int i = 0; i < 32; i++) {
        int o = i * 16 + w * 4 + cg;
        const float* wrow = Wc22 + (size_t)o * 1024;
        float racc[4] = {0.f, 0.f, 0.f, 0.f};
        #pragma unroll
        for (int g = 0; g < 16; g++) {
            int k = g * 64 + kl * 4;
            float4 wv = *(const float4*)(wrow + k);
            #pragma unroll
            for (int r = 0; r < 4; r++) {
                float4 xv = *(const float4*)(x_s + r * 1024 + k);
                racc[r] = fmaf(wv.x, xv.x, racc[r]);
                racc[r] = fmaf(wv.y, xv.y, racc[r]);
                racc[r] = fmaf(wv.z, xv.z, racc[r]);
                racc[r] = fmaf(wv.w, xv.w, racc[r]);
            }
        }
        #pragma unroll
        for (int r = 0; r < 4; r++) {
            racc[r] += __shfl_xor(racc[r], 1, 64);
            racc[r] += __shfl_xor(racc[r], 2, 64);
            racc[r] += __shfl_xor(racc[r], 4, 64);
            racc[r] += __shfl_xor(racc[r], 8, 64);
        }
        if (kl == 0) {
            float bb = bc22[o];
            #pragma unroll
            for (int r = 0; r < 4; r++) y_s[r * 512 + o] = racc[r] + bb;
        }
    }
    __syncthreads();
    // LN row w
    {
        float v[8], sum = 0.f, ssq = 0.f;
        #pragma unroll
        for (int j = 0; j < 8; j++) {
            v[j] = y_s[w * 512 + lane * 8 + j];
            sum += v[j]; ssq += v[j] * v[j];
        }
        #pragma unroll
        for (int m = 1; m < 64; m <<= 1) {
            sum += __shfl_xor(sum, m, 64);
            ssq += __shfl_xor(ssq, m, 64);
        }
        float mu = sum * (1.f / 512.f);
        float rstd = rsqrtf(ssq * (1.f / 512.f) - mu * mu + 1e-5f);
        #pragma unroll
        for (int j = 0; j < 8; j++) {
            int o = lane * 8 + j;
            y_s[w * 512 + o] = (v[j] - mu) * rstd * g2[o] + b2[o];
        }
    }
    __syncthreads();
    // head for row w
    {
        float p[8];
        const float* yp = y_s + w * 512 + lane * 8;
        #pragma unroll
        for (int o8 = 0; o8 < 8; o8++) {
            const float* wp = Wnn1 + o8 * 512 + lane * 8;
            float s = 0.f;
            #pragma unroll
            for (int j = 0; j < 8; j++) s = fmaf(yp[j], wp[j], s);
            p[o8] = s;
        }
        #pragma unroll
        for (int m = 1; m < 64; m <<= 1) {
            #pragma unroll
            for (int o8 = 0; o8 < 8; o8++) p[o8] += __shfl_xor(p[o8], m, 64);
        }
        if (lane == 0) {
            float tv[8], m8 = 0.f;
            #pragma unroll
            for (int o8 = 0; o8 < 8; o8++) {
                tv[o8] = fmaxf(p[o8] + bnn1[o8], 0.f);
                m8 += tv[o8];
            }
            m8 *= 0.125f;
            float var = 0.f;
            #pragma unroll
            for (int o8 = 0; o8 < 8; o8++) { float d = tv[o8] - m8; var += d * d; }
            var *= 0.125f;
            const float rstd8 = rsqrtf(var + 1e-5f);
            float o0v = bnn2[0], o1v = bnn2[1];
            #pragma unroll
            for (int o8 = 0; o8 < 8; o8++) {
                float v = (tv[o8] - m8) * rstd8 * g3[o8] + b3[o8];
                o0v += v * Wnn2[o8];
                o1v += v * Wnn2[8 + o8];
            }
            outt[(row0 + w) * 2 + 0] = o0v;
            outt[(row0 + w) * 2 + 1] = o1v;
        }
    }
}

extern "C" void kernel_launch(void* const* d_in, const int* in_sizes, int n_in,
                              void* d_out, int out_size, void* d_ws, size_t ws_size,
                              hipStream_t stream) {
    const float* X      = (const float*)d_in[0];
    const float* M      = (const float*)d_in[1];
    const float* mask   = (const float*)d_in[2];
    const float* Wi2h   = (const float*)d_in[3];
    const float* bi2h   = (const float*)d_in[4];
    const float* Wcomb1 = (const float*)d_in[5];
    const float* bcomb1 = (const float*)d_in[6];
    const float* Wih1   = (const float*)d_in[7];
    const float* Whh1   = (const float*)d_in[8];
    const float* bih1   = (const float*)d_in[9];
    const float* bhh1   = (const float*)d_in[10];
    const float* Wc21   = (const float*)d_in[11];
    const float* bc21   = (const float*)d_in[12];
    const float* Wcomb2 = (const float*)d_in[13];
    const float* bcomb2 = (const float*)d_in[14];
    const float* Wih2   = (const float*)d_in[15];
    const float* Whh2   = (const float*)d_in[16];
    const float* bih2   = (const float*)d_in[17];
    const float* bhh2   = (const float*)d_in[18];
    const float* Wc22   = (const float*)d_in[19];
    const float* bc22   = (const float*)d_in[20];
    const float* g1     = (const float*)d_in[21];
    const float* b1     = (const float*)d_in[22];
    const float* g2     = (const float*)d_in[23];
    const float* b2     = (const float*)d_in[24];
    const float* g3     = (const float*)d_in[25];
    const float* b3     = (const float*)d_in[26];
    const float* Wnn1   = (const float*)d_in[27];
    const float* bnn1   = (const float*)d_in[28];
    const float* Wnn2   = (const float*)d_in[29];
    const float* bnn2   = (const float*)d_in[30];
    float* out = (float*)d_out;

    // workspace layout (~21.3 MiB) — validated fit in round 3
    const size_t SZ_COMB1 = (size_t)S_ * B_ * 64 * 2;   // 16.78 MB
    const size_t SZ_HX    = (size_t)B_ * H_ * 4;        // 1 MB each
    const size_t SZ_C2T   = (size_t)B_ * 512 * 2;       // 0.52 MB
    const size_t NEED = SZ_COMB1 + 4 * SZ_HX + SZ_C2T + 8192;
    if (ws_size < NEED) {
        float v = 1.0e4f + (float)(ws_size >> 20);
        k_sentinel<<<(out_size + 255) / 256, 256, 0, stream>>>(out, out_size, v);
        return;
    }
    char* ws = (char*)d_ws;
    u16* comb1 = (u16*)ws;   ws += SZ_COMB1;
    float* h1a = (float*)ws; ws += SZ_HX;
    float* h1b = (float*)ws; ws += SZ_HX;
    float* h2a = (float*)ws; ws += SZ_HX;
    float* h2b = (float*)ws; ws += SZ_HX;
    u16* c2t   = (u16*)ws;   ws += SZ_C2T;
    float* beff = (float*)ws; ws += 512 * 4;

    k_h0<<<1024, 256, 0, stream>>>(X, Wi2h, bi2h, h1a, h2a);
    k_beff<<<2, 256, 0, stream>>>(Wcomb2, bcomb2, beff);
    k_comb1<<<8192, 256, 0, stream>>>(X, M, Wcomb1, bcomb1, comb1);

    for (int t = 0; t < S_; t++) {
        const float* h1c = (t & 1) ? h1b : h1a;
        float*       h1n = (t & 1) ? h1a : h1b;
        const float* h2c = (t & 1) ? h2b : h2a;
        float*       h2n = (t & 1) ? h2a : h2b;
        // A1: GRU layer-1 step
        k_gru_step<64><<<dim3(64, 8), 256, 0, stream>>>(
            comb1, Wih1, Whh1, bih1, bhh1, mask, h1c, h1n, t);
        // B1: out1 + LN1 + comb2 slice
        k_out1comb2<<<128, 256, 0, stream>>>(
            comb1 + (size_t)t * B_ * 64, h1n, Wc21, bc21, g1, b1,
            Wcomb2, beff, c2t);
        // A2: GRU layer-2 step
        k_gru_step<512><<<dim3(64, 8), 256, 0, stream>>>(
            c2t, Wih2, Whh2, bih2, bhh2, mask + (size_t)t * B_, h2c, h2n, 0);
        // B2: out2 + LN2 + head -> out[t]
        k_out2head<<<128, 256, 0, stream>>>(
            c2t, h2n, Wc22, bc22, g2, b2, Wnn1, bnn1, g3, b3, Wnn2, bnn2,
            out + (size_t)t * B_ * 2);
    }
}